// Round 19
// baseline (129520.251 us; speedup 1.0000x reference)
//
#include <hip/hip_runtime.h>

#define TT    1024
#define NTHR  512
#define NWG   256

// ---- per-XCD state block (float offsets within block) ----
#define XB_SZ  65536           // floats per XCD (256 KB)
#define XA0    0               // ahx0: 2 x 8 x 128
#define XA1    2048            // ahx1: 2 x 8 x 128
#define XF0    4096            // fhx0: 2 x 8 x 512
#define XF1    12288           // fhx1: 2 x 8 x 512
#define XP0    20480           // pol0: 8 x 2560
#define XP1    40960           // pol1: 8 x 2560
#define X_ZERO_END 20480

#define O_BARB (8 * XB_SZ)     // barrier block float offset
// bar ints: cnt[xcd]=xcd*256, epoch[xcd]=xcd*256+64, roster[xcd]=2048+xcd

// ---- LDS layout (float offsets), padded rows to spread banks ----
#define L_F0O  0               // fhx0_o: 8 rows x 520 (512 used)
#define L_F0N  4160            // fhx0_n
#define L_F1O  8320            // fhx1_o
#define L_A1O  12480           // ahx1_o: 8 x 136 (128 used)
#define L_A0O  13568           // ahx0_o
#define L_A0N  14656           // ahx0_n
#define L_A1N  15744           // ahx1_n
#define L_POL  16832           // pol stage: 8 x 2568 (2560 used)
#define LDS_F  37376           // 149,504 B -> 1 WG/CU (pigeonhole)

__device__ __forceinline__ float sigm(float x) { return 1.f / (1.f + __expf(-x)); }

// ---- staging: global (relaxed agent-atomic 8B, bypasses L1, served by the
// shared XCD L2 incl. dirty lines) -> padded LDS rows ----
template <int RW2, int LS2>
__device__ __forceinline__ void stage_r(const float* g, float* l, int rows, int tid) {
  const unsigned long long* gs = (const unsigned long long*)g;
  unsigned long long* ls = (unsigned long long*)l;
  const int tot = rows * RW2;
  for (int i = tid; i < tot; i += NTHR) {
    int rr = i / RW2, cc = i - rr * RW2;
    ls[rr * LS2 + cc] = __hip_atomic_load(&gs[i], __ATOMIC_RELAXED,
                                          __HIP_MEMORY_SCOPE_AGENT);
  }
}

// K-sliced dot: thread ks takes float4 #(k*4+ks).
__device__ __forceinline__ float dot_ks(const float* __restrict__ a,
                                        const float* __restrict__ w,
                                        int nq, int ks) {
  float s0=0.f,s1=0.f,s2=0.f,s3=0.f;
  const float4* a4=(const float4*)a; const float4* w4=(const float4*)w;
  #pragma unroll 8
  for (int k = 0; k < nq; ++k) {
    int i4 = (k<<2) + ks;
    float4 av = a4[i4], wv = w4[i4];
    s0=fmaf(av.x,wv.x,s0); s1=fmaf(av.y,wv.y,s1);
    s2=fmaf(av.z,wv.z,s2); s3=fmaf(av.w,wv.w,s3);
  }
  return (s0+s1)+(s2+s3);
}
__device__ __forceinline__ float dot3_ks(const float* __restrict__ a,
                                         const float* __restrict__ pp,
                                         const float* __restrict__ w,
                                         int nq, int ks) {
  float s0=0.f,s1=0.f,s2=0.f,s3=0.f;
  const float4* a4=(const float4*)a; const float4* p4=(const float4*)pp;
  const float4* w4=(const float4*)w;
  #pragma unroll 8
  for (int k = 0; k < nq; ++k) {
    int i4 = (k<<2) + ks;
    float4 av = a4[i4], pv = p4[i4], wv = w4[i4];
    s0=fmaf(av.x*pv.x,wv.x,s0); s1=fmaf(av.y*pv.y,wv.y,s1);
    s2=fmaf(av.z*pv.z,wv.z,s2); s3=fmaf(av.w*pv.w,wv.w,s3);
  }
  return (s0+s1)+(s2+s3);
}
__device__ __forceinline__ float dot_full(const float* __restrict__ a,
                                          const float* __restrict__ w) {
  float s0=0.f,s1=0.f,s2=0.f,s3=0.f;
  const float4* a4=(const float4*)a; const float4* w4=(const float4*)w;
  #pragma unroll 8
  for (int k = 0; k < 32; ++k) {
    float4 av = a4[k], wv = w4[k];
    s0=fmaf(av.x,wv.x,s0); s1=fmaf(av.y,wv.y,s1);
    s2=fmaf(av.z,wv.z,s2); s3=fmaf(av.w,wv.w,s3);
  }
  return (s0+s1)+(s2+s3);
}

// ---- intra-XCD barrier: FULLY RELAXED (R15-proven protocol; zero cache
// maintenance). Producer stores drain to the shared XCD L2 at __syncthreads
// (per-wave vmcnt) before the arrive-RMW; epoch store issues after all 32
// arrivals; consumers' subsequent STAGING reads are agent-atomics served by
// the same L2 -> no acquire/invalidate needed anywhere.
__device__ __forceinline__ void xbar(int* cnt, int* ep, int e, int tid) {
  __syncthreads();
  if (tid == 0) {
    int old = __hip_atomic_fetch_add(cnt, 1, __ATOMIC_RELAXED,
                                     __HIP_MEMORY_SCOPE_AGENT);
    if (old == e * 32 - 1)
      __hip_atomic_store(ep, e, __ATOMIC_RELAXED, __HIP_MEMORY_SCOPE_AGENT);
    while (__hip_atomic_load(ep, __ATOMIC_RELAXED,
                             __HIP_MEMORY_SCOPE_AGENT) < e)
      __builtin_amdgcn_s_sleep(1);
  }
  __syncthreads();
}

struct Params {
  const float* x;
  const float *aW_ih0, *aW_hh0, *ab_ih0, *ab_hh0, *pW0, *pb0, *fW_ih0, *fW_hh0, *fb0;
  const float *aW_ih1, *aW_hh1, *ab_ih1, *ab_hh1, *pW1, *pb1, *fW_ih1, *fW_hh1, *fb1;
  float* out;
  float* ws;
};

__global__ __launch_bounds__(NTHR, 1)
void arnn_kernel(Params p) {
  extern __shared__ float lds[];
  __shared__ int s_rank;
  const int tid = threadIdx.x;
  float* __restrict__ ws = p.ws;

  int xcd;
  asm volatile("s_getreg_b32 %0, hwreg(HW_REG_XCC_ID)" : "=s"(xcd));
  xcd &= 7;

  int* bar = (int*)(ws + O_BARB);
  if (tid == 0)
    s_rank = __hip_atomic_fetch_add(&bar[2048 + xcd], 1,
                                    __ATOMIC_RELAXED, __HIP_MEMORY_SCOPE_AGENT);
  __syncthreads();
  const int r = s_rank;              // rank 0..31 within this XCD
  int* cnt = &bar[xcd * 256];
  int* ep  = &bar[xcd * 256 + 64];

  float* xb = ws + (size_t)xcd * XB_SZ;
  const int b0 = xcd * 8;            // this XCD owns batches b0..b0+7

  // zero this XCD's recurrent state (drained to L2 by first xbar)
  for (int i = r * NTHR + tid; i < X_ZERO_END; i += 32 * NTHR) xb[i] = 0.f;

  // ---- thread maps (R12-proven) ----
  const int lane = tid & 63;
  const int ks   = tid & 3;
  const int jj = tid >> 7, blL = (tid >> 4) & 7, q = (tid >> 2) & 3;
  const int jL = r * 4 + jj;
  const bool cell = (tid & 15) == 0;
  const int c4 = tid >> 5, blA = (tid >> 2) & 7;
  const int cA = r * 16 + c4;
  const int nAr = tid >> 3, blP = tid & 7;
  const int nA = r * 80 + nAr;
  const int nB = r * 80 + 64 + nAr;  // valid if tid < 128

  float bi0=0,bf0=0,bg0=0,bo0=0, bi1=0,bf1=0,bg1=0,bo1=0;
  if (cell) {
    bi0 = p.ab_ih0[0*128+jL] + p.ab_hh0[0*128+jL];
    bf0 = p.ab_ih0[1*128+jL] + p.ab_hh0[1*128+jL];
    bg0 = p.ab_ih0[2*128+jL] + p.ab_hh0[2*128+jL];
    bo0 = p.ab_ih0[3*128+jL] + p.ab_hh0[3*128+jL];
    bi1 = p.ab_ih1[0*128+jL] + p.ab_hh1[0*128+jL];
    bf1 = p.ab_ih1[1*128+jL] + p.ab_hh1[1*128+jL];
    bg1 = p.ab_ih1[2*128+jL] + p.ab_hh1[2*128+jL];
    bo1 = p.ab_ih1[3*128+jL] + p.ab_hh1[3*128+jL];
  }
  const float fb0c = p.fb0[cA], fb1c = p.fb1[cA];
  const float pb0a = p.pb0[nA], pb1a = p.pb1[nA];
  float pb0b = 0.f, pb1b = 0.f;
  if (tid < 128) { pb0b = p.pb0[nB]; pb1b = p.pb1[nB]; }

  // ---- weight row pointers (read-only: normal cached loads, no staleness) ----
  const int rowL = q * 128 + jL;
  const float* wih0 = p.aW_ih0 + (size_t)rowL * 1152;
  const float* whh0 = p.aW_hh0 + (size_t)rowL * 128;
  const float* wih1 = p.aW_ih1 + (size_t)rowL * 1152;
  const float* whh1 = p.aW_hh1 + (size_t)rowL * 128;
  const float* fwi0 = p.fW_ih0 + (size_t)cA * 512;
  const float* fwh0 = p.fW_hh0 + (size_t)cA * 512;
  const float* fwi1 = p.fW_ih1 + (size_t)cA * 512;
  const float* fwh1 = p.fW_hh1 + (size_t)cA * 512;

  float creg0 = 0.f, creg1 = 0.f;    // LSTM cell states (thread-resident)

  int e = 1;
  xbar(cnt, ep, e, tid);

  for (int t = 0; t < TT; ++t) {
    const int old = t & 1, nw = old ^ 1;
    float* ahx0_o = xb + XA0 + old * 1024;
    float* ahx0_n = xb + XA0 + nw  * 1024;
    float* ahx1_o = xb + XA1 + old * 1024;
    float* ahx1_n = xb + XA1 + nw  * 1024;
    float* fhx0_o = xb + XF0 + old * 4096;
    float* fhx0_n = xb + XF0 + nw  * 4096;
    float* fhx1_o = xb + XF1 + old * 4096;
    float* fhx1_n = xb + XF1 + nw  * 4096;
    float* pol0   = xb + XP0;
    float* pol1   = xb + XP1;
    const float* xt = p.x + ((size_t)t * 64 + b0) * 512;

    // ---- P0: LSTM0 ----
    stage_r<256,260>(fhx0_o, lds + L_F0O, 8, tid);
    stage_r<64,68>  (ahx1_o, lds + L_A1O, 8, tid);
    stage_r<64,68>  (ahx0_o, lds + L_A0O, 8, tid);
    __syncthreads();
    {
      float s = dot_ks(xt + blL * 512,          wih0,        32, ks)
              + dot_ks(lds + L_F0O + blL * 520, wih0 + 512,  32, ks)
              + dot_ks(lds + L_A1O + blL * 136, wih0 + 1024,  8, ks)
              + dot_ks(lds + L_A0O + blL * 136, whh0,         8, ks);
      s += __shfl_xor(s, 1); s += __shfl_xor(s, 2);
      float gi = __shfl(s,(lane&48)+0),  gf = __shfl(s,(lane&48)+4);
      float gg = __shfl(s,(lane&48)+8),  go = __shfl(s,(lane&48)+12);
      if (cell) {
        gi += bi0; gf += bf0; gg += bg0; go += bo0;
        float c2 = sigm(gf) * creg0 + sigm(gi) * tanhf(gg);
        creg0 = c2;
        ahx0_n[blL * 128 + jL] = sigm(go) * tanhf(c2);
      }
    }
    ++e; xbar(cnt, ep, e, tid);

    // ---- P1: pol0 ----
    stage_r<64,68>(ahx0_n, lds + L_A0N, 8, tid);
    __syncthreads();
    {
      pol0[blP * 2560 + nA] = pb0a +
          dot_full(lds + L_A0N + blP * 136, p.pW0 + (size_t)nA * 128);
      if (tid < 128)
        pol0[blP * 2560 + nB] = pb0b +
            dot_full(lds + L_A0N + blP * 136, p.pW0 + (size_t)nB * 128);
    }
    ++e; xbar(cnt, ep, e, tid);

    // ---- P2: aRNN0 ----
    stage_r<1280,1284>(pol0, lds + L_POL, 8, tid);
    __syncthreads();
    {
      const float* prl = lds + L_POL + blA * 2568;
      float sig = dot3_ks(xt + blA * 512,          prl,       fwi0, 32, ks);
      float shg = dot3_ks(lds + L_F0O + blA * 520, prl + 512, fwh0, 32, ks);
      sig += __shfl_xor(sig, 1); sig += __shfl_xor(sig, 2);
      shg += __shfl_xor(shg, 1); shg += __shfl_xor(shg, 2);
      if (ks == 0) {
        float v = tanhf(sig * prl[1024 + cA] + fb0c * prl[2048 + cA]
                      + shg * prl[1536 + cA]);
        fhx0_n[blA * 512 + cA] = v;
      }
    }
    ++e; xbar(cnt, ep, e, tid);

    // ---- P3: LSTM1 (ahx0_n staged @P1, ahx1_o staged @P0 still resident) ----
    stage_r<256,260>(fhx0_n, lds + L_F0N, 8, tid);
    stage_r<256,260>(fhx1_o, lds + L_F1O, 8, tid);
    __syncthreads();
    {
      float s = dot_ks(lds + L_F0N + blL * 520, wih1,        32, ks)
              + dot_ks(lds + L_F1O + blL * 520, wih1 + 512,  32, ks)
              + dot_ks(lds + L_A0N + blL * 136, wih1 + 1024,  8, ks)
              + dot_ks(lds + L_A1O + blL * 136, whh1,         8, ks);
      s += __shfl_xor(s, 1); s += __shfl_xor(s, 2);
      float gi = __shfl(s,(lane&48)+0),  gf = __shfl(s,(lane&48)+4);
      float gg = __shfl(s,(lane&48)+8),  go = __shfl(s,(lane&48)+12);
      if (cell) {
        gi += bi1; gf += bf1; gg += bg1; go += bo1;
        float c2 = sigm(gf) * creg1 + sigm(gi) * tanhf(gg);
        creg1 = c2;
        ahx1_n[blL * 128 + jL] = sigm(go) * tanhf(c2);
      }
    }
    ++e; xbar(cnt, ep, e, tid);

    // ---- P4: pol1 ----
    stage_r<64,68>(ahx1_n, lds + L_A1N, 8, tid);
    __syncthreads();
    {
      pol1[blP * 2560 + nA] = pb1a +
          dot_full(lds + L_A1N + blP * 136, p.pW1 + (size_t)nA * 128);
      if (tid < 128)
        pol1[blP * 2560 + nB] = pb1b +
            dot_full(lds + L_A1N + blP * 136, p.pW1 + (size_t)nB * 128);
    }
    ++e; xbar(cnt, ep, e, tid);

    // ---- P5: aRNN1 + output (fhx0_n/fhx1_o staged @P3 still resident) ----
    stage_r<1280,1284>(pol1, lds + L_POL, 8, tid);
    __syncthreads();
    {
      const float* prl = lds + L_POL + blA * 2568;
      float sig = dot3_ks(lds + L_F0N + blA * 520, prl,       fwi1, 32, ks);
      float shg = dot3_ks(lds + L_F1O + blA * 520, prl + 512, fwh1, 32, ks);
      sig += __shfl_xor(sig, 1); sig += __shfl_xor(sig, 2);
      shg += __shfl_xor(shg, 1); shg += __shfl_xor(shg, 2);
      if (ks == 0) {
        float v = tanhf(sig * prl[1024 + cA] + fb1c * prl[2048 + cA]
                      + shg * prl[1536 + cA]);
        fhx1_n[blA * 512 + cA] = v;
        p.out[((size_t)t * 64 + b0 + blA) * 512 + cA] = v;
      }
    }
    ++e; xbar(cnt, ep, e, tid);
  }
}

extern "C" void kernel_launch(void* const* d_in, const int* in_sizes, int n_in,
                              void* d_out, int out_size, void* d_ws, size_t ws_size,
                              hipStream_t stream) {
  Params prm;
  prm.x      = (const float*)d_in[0];
  prm.aW_ih0 = (const float*)d_in[1];
  prm.aW_hh0 = (const float*)d_in[2];
  prm.ab_ih0 = (const float*)d_in[3];
  prm.ab_hh0 = (const float*)d_in[4];
  prm.pW0    = (const float*)d_in[5];
  prm.pb0    = (const float*)d_in[6];
  prm.fW_ih0 = (const float*)d_in[7];
  prm.fW_hh0 = (const float*)d_in[8];
  prm.fb0    = (const float*)d_in[9];
  prm.aW_ih1 = (const float*)d_in[10];
  prm.aW_hh1 = (const float*)d_in[11];
  prm.ab_ih1 = (const float*)d_in[12];
  prm.ab_hh1 = (const float*)d_in[13];
  prm.pW1    = (const float*)d_in[14];
  prm.pb1    = (const float*)d_in[15];
  prm.fW_ih1 = (const float*)d_in[16];
  prm.fW_hh1 = (const float*)d_in[17];
  prm.fb1    = (const float*)d_in[18];
  prm.out    = (float*)d_out;
  prm.ws     = (float*)d_ws;

  // zero barrier counters/epochs/roster (deterministic replays)
  hipMemsetAsync((char*)d_ws + (size_t)O_BARB * 4, 0, 16384, stream);

  static int lds_bytes = LDS_F * 4;   // 146 KB -> 1 WG/CU (pigeonhole)
  hipFuncSetAttribute((const void*)arnn_kernel,
                      hipFuncAttributeMaxDynamicSharedMemorySize, lds_bytes);

  void* kargs[] = { (void*)&prm };
  hipLaunchCooperativeKernel((const void*)arnn_kernel, dim3(NWG), dim3(NTHR),
                             kargs, lds_bytes, stream);
}